// Round 8
// baseline (408.674 us; speedup 1.0000x reference)
//
#include <hip/hip_runtime.h>

// ---------------------------------------------------------------------------
// GatingNetworkWithTopK: h = relu(x@W1+b1); g = softmax(h@W2+b2);
// top-1 mask; out = masked / (colsum+1e-4) * 32768
//
// R3: single-plane fp16 GEMM1 (absmax 55.5 vs thr 149.76) - FROZEN.
// R4 coarse counted-vmcnt: REGRESS. R5 dispatch fusion: NEUTRAL.
// R6 LDS-traffic cut: NULL. R7 occupancy push: SPILLED.
// R8 256x256 8-wave phased (bunched staging, depth-1): NEUTRAL (197us) but
//     correct (absmax 55.5), FETCH 280->148MB.
// R9 m201-style per-phase interleave: WRONG K BOUND (64 half-tiles x BK32 =
//     2048 > K=1024; read past row end -> absmax 7488). Schedule untested.
// R10: R9 with kt<32 (32 half-tiles x BK32 = 1024 = K). Tail gates
//     re-derived: stage while kt<=28; vmcnt(8) kt<29 / vmcnt(4) kt=29 /
//     vmcnt(0) kt=30. K accumulation order bit-identical -> absmax 55.5.
// ---------------------------------------------------------------------------

typedef float f32x4 __attribute__((ext_vector_type(4)));
typedef float f32x16 __attribute__((ext_vector_type(16)));
typedef __bf16 bf16x8 __attribute__((ext_vector_type(8)));
typedef _Float16 f16x8 __attribute__((ext_vector_type(8)));
typedef unsigned short u16x4 __attribute__((ext_vector_type(4)));

#define NTOK 32768
#define DIN 1024
#define DH 2048
#define NE 16

__device__ __forceinline__ unsigned short f2bf(float f) {
  unsigned u = __float_as_uint(f);
  u += 0x7FFFu + ((u >> 16) & 1u);
  return (unsigned short)(u >> 16);
}
__device__ __forceinline__ float bf2f(unsigned short s) {
  return __uint_as_float(((unsigned)s) << 16);
}

__device__ __forceinline__ void async16(const void* g, void* s) {
  __builtin_amdgcn_global_load_lds((const __attribute__((address_space(1))) void*)g,
                                   (__attribute__((address_space(3))) void*)s, 16, 0, 0);
}

// ---------------- prep: convert x, transpose+convert W1, W2 frags -----------
// block ranges: [0,16384) convert_x | [16384,18432) W1^T | [18432,18448) W2
__global__ void prep_k(const float* __restrict__ x, _Float16* __restrict__ xh,
                       const float* __restrict__ W1, _Float16* __restrict__ wh,
                       const float* __restrict__ W2, unsigned short* __restrict__ w2fh,
                       unsigned short* __restrict__ w2fl, float* __restrict__ denom,
                       unsigned int* __restrict__ cnt) {
  __shared__ float tile[32][33];
  const int b = blockIdx.x;
  if (b < 16384) {
    // ---- convert x -> fp16 ----
    size_t i = (size_t)b * 256 + threadIdx.x;
    f32x4 a = ((const f32x4*)x)[i * 2];
    f32x4 c = ((const f32x4*)x)[i * 2 + 1];
    f16x8 o;
#pragma unroll
    for (int j = 0; j < 4; ++j) {
      o[j] = (_Float16)a[j];
      o[j + 4] = (_Float16)c[j];
    }
    ((f16x8*)xh)[i] = o;
  } else if (b < 16384 + 2048) {
    // ---- transpose + convert W1 [K][N] -> [N][K] ----
    const int idx = b - 16384;
    const int nt = idx & 63;
    const int kt = idx >> 6;
    const int c = threadIdx.x & 31, r0 = threadIdx.x >> 5;
#pragma unroll
    for (int i = 0; i < 4; ++i) {
      int k = (kt << 5) + r0 + (i << 3);
      tile[r0 + (i << 3)][c] = W1[(size_t)k * DH + (nt << 5) + c];
    }
    __syncthreads();
#pragma unroll
    for (int i = 0; i < 4; ++i) {
      int n = (nt << 5) + r0 + (i << 3);
      wh[(size_t)n * DIN + (kt << 5) + c] = (_Float16)tile[c][r0 + (i << 3)];
    }
  } else {
    // ---- W2 [2048][16] -> MFMA-16x16x32 B-fragment order, hi/lo planes ----
    const int bb = b - 18432;
    const int t = bb * 256 + threadIdx.x;
    const int kstep = t >> 6, l = t & 63;
    const int q = l >> 4, e = l & 15;
    u16x4 h0, h1, l0, l1;
#pragma unroll
    for (int j = 0; j < 8; ++j) {
      float v = W2[(size_t)((kstep << 5) + (q << 3) + j) * NE + e];
      unsigned short hh = f2bf(v);
      unsigned short ll = f2bf(v - bf2f(hh));
      if (j < 4) { h0[j] = hh; l0[j] = ll; } else { h1[j - 4] = hh; l1[j - 4] = ll; }
    }
    ((u16x4*)w2fh)[t * 2] = h0;
    ((u16x4*)w2fh)[t * 2 + 1] = h1;
    ((u16x4*)w2fl)[t * 2] = l0;
    ((u16x4*)w2fl)[t * 2 + 1] = l1;
    if (bb == 0) {
      if (threadIdx.x < 16) denom[threadIdx.x] = 0.0f;
      if (threadIdx.x == 16) *cnt = 0u;
    }
  }
}

// ------------------------- fused GEMM1 + partial logits ---------------------
// Block tile 256x256, 8 waves (2M x 4N, wave tile 128x64), K in BK=32
// half-tiles (32 total = K 1024). LDS: 4-deep ring of 32KB [A 16K | B 16K].
// Half-tile = 256 rows x 64B = 1024 A + 1024 B chunks of 16B; thread t owns
// A chunks {t, t+512}, B chunks {t, t+512} (2 gloads per phase).
// Chunk c -> LDS (row=c>>2, slot=c&3); content = global slot
// (c&3)^((c>>3)&3) (both-sides XOR swizzle, R4/R6-verified for 64B rows).
__global__ __launch_bounds__(512, 1) void gemm1_fused_k(
    const _Float16* __restrict__ xh, const _Float16* __restrict__ wh,
    const unsigned short* __restrict__ w2fh, const unsigned short* __restrict__ w2fl,
    const float* __restrict__ b1, _Float16* __restrict__ plogh) {
  __shared__ unsigned char smem[131072];
  const int t = threadIdx.x;
  const int w = t >> 6;
  const int l = t & 63;
  const int la = l & 31;
  const int half = l >> 5;
  const int rs = (la >> 1) & 3;  // read-side swizzle (row>>1)&3; warow/i*32 are 0 mod 8
  // bijective XCD-aware map: xcd = orig&7 owns 16 contiguous row-panels
  const int orig = blockIdx.x;
  const int idx = orig >> 3;
  const int by = ((orig & 7) << 4) | (idx & 15);  // 0..127
  const int bx = idx >> 4;                        // 0..7
  const int rowBase = by << 8;   // 256 tokens
  const int colBase = bx << 8;   // 256 hidden cols
  const int warow = (w >> 2) << 7;  // {0,128}
  const int wacol = (w & 3) << 6;   // {0,64,128,192}

  // staging pointers: k in {0,1} -> chunk c = t + k*512
  const _Float16* sgA[2];
  const _Float16* sgB[2];
  int loffA[2], loffB[2];
#pragma unroll
  for (int k = 0; k < 2; ++k) {
    const int c = t + (k << 9);  // 0..1023
    const int row = c >> 2;
    const int sl = (c & 3) ^ ((c >> 3) & 3);
    sgA[k] = xh + (size_t)(rowBase + row) * DIN + (sl << 3);
    sgB[k] = wh + (size_t)(colBase + row) * DIN + (sl << 3);
    loffA[k] = c << 4;
    loffB[k] = 16384 + (c << 4);
  }

  f32x16 acc[4][2] = {};

  // prologue: prefetch half-tiles 0,1,2 (depth 3; 12 loads/thread in flight)
#pragma unroll
  for (int j = 0; j < 3; ++j) {
    unsigned char* nb = smem + ((j & 3) << 15);
#pragma unroll
    for (int k = 0; k < 2; ++k) {
      async16(sgA[k] + (j << 5), nb + loffA[k]);
      async16(sgB[k] + (j << 5), nb + loffB[k]);
    }
  }
  // gate half-tile 0 (12 outstanding -> wait oldest 4)
  asm volatile("s_waitcnt vmcnt(8)\n\ts_barrier" ::: "memory");

#pragma unroll 1
  for (int kt = 0; kt < 32; ++kt) {
    const unsigned char* cb = smem + ((kt & 3) << 15);
    unsigned char* nb = smem + (((kt + 3) & 3) << 15);
    const bool do_stage = (kt + 3) < 32;
#pragma unroll
    for (int s = 0; s < 2; ++s) {
      // --- stage: 2 global_load_lds for half-tile kt+3 (one chunk-pair) ---
      if (do_stage) {
        async16(sgA[s] + ((kt + 3) << 5), nb + loffA[s]);
        async16(sgB[s] + ((kt + 3) << 5), nb + loffB[s]);
      }
      // --- ds_read 6 frags for K16-sub s ---
      const int cs = (((s << 1) + half) ^ rs) << 4;
      f16x8 a[4], b[2];
#pragma unroll
      for (int i = 0; i < 4; ++i)
        a[i] = *(const f16x8*)(cb + ((warow + (i << 5) + la) << 6) + cs);
#pragma unroll
      for (int j = 0; j < 2; ++j)
        b[j] = *(const f16x8*)(cb + 16384 + ((wacol + (j << 5) + la) << 6) + cs);
      asm volatile("s_barrier" ::: "memory");
      __builtin_amdgcn_s_setprio(1);
#pragma unroll
      for (int i = 0; i < 4; ++i)
#pragma unroll
        for (int j = 0; j < 2; ++j)
          acc[i][j] = __builtin_amdgcn_mfma_f32_32x32x16_f16(a[i], b[j], acc[i][j], 0, 0, 0);
      __builtin_amdgcn_s_setprio(0);
      if (s == 1) {
        // gate for half-tile kt+1, folded into the trailing barrier.
        // stages exist for tiles <=31 (issued while kt<=28).
        if (kt < 29)
          asm volatile("s_waitcnt vmcnt(8)" ::: "memory");  // 12 out -> tile kt+1 done
        else if (kt == 29)
          asm volatile("s_waitcnt vmcnt(4)" ::: "memory");  // 8 out -> tile 30 done
        else if (kt == 30)
          asm volatile("s_waitcnt vmcnt(0)" ::: "memory");  // 4 out -> tile 31 done
      }
      asm volatile("s_barrier" ::: "memory");
    }
  }
  __syncthreads();

  // ---- epilogue: bias + relu (keep exact fp32 h in acc) ----
  float b1v[2];
#pragma unroll
  for (int j = 0; j < 2; ++j) b1v[j] = b1[colBase + wacol + (j << 5) + la];
#pragma unroll
  for (int i = 0; i < 4; ++i)
#pragma unroll
    for (int j = 0; j < 2; ++j)
#pragma unroll
      for (int r = 0; r < 16; ++r) acc[i][j][r] = fmaxf(acc[i][j][r] + b1v[j], 0.0f);

  f32x4 pacc[2] = {};
  const int q16 = l >> 4;
  const int e16 = l & 15;
  const int myhalf = (w & 3) >> 1;  // which 128-col half this wave owns

  // two column halves of 128; per half: hi-plane pass (hh+hl) then lo (lh)
#pragma unroll
  for (int ch = 0; ch < 2; ++ch) {
    // ---- hi plane -> LDS (256 rows, stride 136 bf16 = 272B) ----
    if (myhalf == ch) {
#pragma unroll
      for (int i = 0; i < 4; ++i)
#pragma unroll
        for (int j = 0; j < 2; ++j)
#pragma unroll
          for (int r = 0; r < 16; ++r) {
            const int rowl = warow + (i << 5) + (r & 3) + ((r >> 2) << 3) + (half << 2);
            const int coll = (wacol & 127) + (j << 5) + la;
            *(unsigned short*)(smem + rowl * 272 + (coll << 1)) = f2bf(acc[i][j][r]);
          }
    }
    __syncthreads();
#pragma unroll
    for (int tm = 0; tm < 2; ++tm) {
      const int tok = ((w * 2 + tm) << 4) + e16;
#pragma unroll
      for (int s = 0; s < 4; ++s) {
        bf16x8 a = *(const bf16x8*)(smem + tok * 272 + (s << 6) + (q16 << 4));
        const size_t gs = (size_t)(((colBase >> 5) + (ch << 2) + s) << 6);
        bf16x8 vbh = *(const bf16x8*)(w2fh + ((gs + l) << 3));
        bf16x8 vbl = *(const bf16x8*)(w2fl + ((gs + l) << 3));
        pacc[tm] = __builtin_amdgcn_mfma_f32_16x16x32_bf16(a, vbh, pacc[tm], 0, 0, 0);
        pacc[tm] = __builtin_amdgcn_mfma_f32_16x16x32_bf16(a, vbl, pacc[tm], 0, 0, 0);
      }
    }
    __syncthreads();
    // ---- lo plane ----
    if (myhalf == ch) {
#pragma unroll
      for (int i = 0; i < 4; ++i)
#pragma unroll
        for (int j = 0; j < 2; ++j)
#pragma unroll
          for (int r = 0; r < 16; ++r) {
            const int rowl = warow + (i << 5) + (r & 3) + ((r >> 2) << 3) + (half << 2);
            const int coll = (wacol & 127) + (j << 5) + la;
            const float v = acc[i][j][r];
            *(unsigned short*)(smem + rowl * 272 + (coll << 1)) = f2bf(v - bf2f(f2bf(v)));
          }
    }
    __syncthreads();
#pragma unroll
    for (int tm = 0; tm < 2; ++tm) {
      const int tok = ((w * 2 + tm) << 4) + e16;
#pragma unroll
      for (int s = 0; s < 4; ++s) {
        bf16x8 a = *(const bf16x8*)(smem + tok * 272 + (s << 6) + (q16 << 4));
        const size_t gs = (size_t)(((colBase >> 5) + (ch << 2) + s) << 6);
        bf16x8 vbh = *(const bf16x8*)(w2fh + ((gs + l) << 3));
        pacc[tm] = __builtin_amdgcn_mfma_f32_16x16x32_bf16(a, vbh, pacc[tm], 0, 0, 0);
      }
    }
    __syncthreads();
  }

  // ---- store partial logits (fp16): plog[bx][rowBase+token][e] ----
#pragma unroll
  for (int tm = 0; tm < 2; ++tm)
#pragma unroll
    for (int r = 0; r < 4; ++r) {
      const int tokl = ((w * 2 + tm) << 4) + (q16 << 2) + r;
      plogh[((size_t)bx << 19) + ((size_t)(rowBase + tokl) << 4) + e16] =
          (_Float16)pacc[tm][r];
    }
}

// -------- reduce partials + softmax + argmax + denom + finalize -------------
// 128 blocks x 256 threads; all blocks co-resident on 256 CUs -> device-scope
// spin barrier after denom accumulation, then finalize in-place.
__global__ void reduce_finalize_k(const _Float16* __restrict__ plogh,
                                  const float* __restrict__ b2, float* __restrict__ denom,
                                  unsigned int* __restrict__ cnt, float* __restrict__ out) {
  const int tok = blockIdx.x * 256 + threadIdx.x;
  float lg[16];
#pragma unroll
  for (int e = 0; e < 16; ++e) lg[e] = b2[e];
  for (int p = 0; p < 8; ++p) {
    const f16x8* q = (const f16x8*)(plogh + ((size_t)p << 19) + ((size_t)tok << 4));
    f16x8 v0 = q[0];
    f16x8 v1 = q[1];
#pragma unroll
    for (int j = 0; j < 8; ++j) {
      lg[j] += (float)v0[j];
      lg[8 + j] += (float)v1[j];
    }
  }
  float m = lg[0];
  int idx = 0;
#pragma unroll
  for (int e = 1; e < 16; ++e)
    if (lg[e] > m) { m = lg[e]; idx = e; }
  float se = 0.0f;
#pragma unroll
  for (int e = 0; e < 16; ++e) se += expf(lg[e] - m);
  const float pt = 1.0f / se;

  __shared__ float sden[16];
  if (threadIdx.x < 16) sden[threadIdx.x] = 0.0f;
  __syncthreads();
  atomicAdd(&sden[idx], pt);
  __syncthreads();
  if (threadIdx.x < 16) atomicAdd(&denom[threadIdx.x], sden[threadIdx.x]);
  // release: make this block's denom adds device-visible before signaling
  __threadfence();
  __syncthreads();
  if (threadIdx.x == 0) {
    atomicAdd(cnt, 1u);
    while (__hip_atomic_load(cnt, __ATOMIC_ACQUIRE, __HIP_MEMORY_SCOPE_AGENT) < gridDim.x)
      __builtin_amdgcn_s_sleep(4);
  }
  __syncthreads();
  const float dv =
      __hip_atomic_load(&denom[idx], __ATOMIC_RELAXED, __HIP_MEMORY_SCOPE_AGENT);
  const float v = pt / (dv + 1e-4f) * 32768.0f;
  f32x4* q4 = (f32x4*)(out + ((size_t)tok << 4));
#pragma unroll
  for (int g = 0; g < 4; ++g) {
    f32x4 o;
#pragma unroll
    for (int j = 0; j < 4; ++j) o[j] = ((g * 4 + j) == idx) ? v : 0.0f;
    q4[g] = o;
  }
}

// ---------------------------------------------------------------------------
extern "C" void kernel_launch(void* const* d_in, const int* in_sizes, int n_in, void* d_out,
                              int out_size, void* d_ws, size_t ws_size, hipStream_t stream) {
  (void)in_sizes; (void)n_in; (void)out_size; (void)ws_size;
  const float* x = (const float*)d_in[0];
  const float* W1 = (const float*)d_in[1];
  const float* b1 = (const float*)d_in[2];
  const float* W2 = (const float*)d_in[3];
  const float* b2 = (const float*)d_in[4];
  float* out = (float*)d_out;

  char* p = (char*)d_ws;
  _Float16* xhp = (_Float16*)p; p += (size_t)NTOK * DIN * 2;
  _Float16* whp = (_Float16*)p; p += (size_t)DH * DIN * 2;
  unsigned short* w2fh = (unsigned short*)p; p += (size_t)64 * 64 * 8 * 2;
  unsigned short* w2fl = (unsigned short*)p; p += (size_t)64 * 64 * 8 * 2;
  _Float16* plogh = (_Float16*)p; p += (size_t)8 * NTOK * NE * 2;
  float* denom = (float*)p; p += 64;
  unsigned int* cnt = (unsigned int*)p; p += 64;

  prep_k<<<18448, 256, 0, stream>>>(x, xhp, W1, whp, W2, w2fh, w2fl, denom, cnt);
  gemm1_fused_k<<<1024, 512, 0, stream>>>(xhp, whp, w2fh, w2fl, b1, plogh);
  reduce_finalize_k<<<128, 256, 0, stream>>>(plogh, b2, denom, cnt, out);
}